// Round 18
// baseline (841.953 us; speedup 1.0000x reference)
//
#include <hip/hip_runtime.h>

#define TT 256
#define BATCH 2048
#define DATA 32
#define WSLOTS 52

typedef __bf16 bf16x8 __attribute__((ext_vector_type(8)));
typedef float f32x4 __attribute__((ext_vector_type(4)));

#define MFMA(A, B, C) __builtin_amdgcn_mfma_f32_16x16x32_bf16((A), (B), (C), 0, 0, 0)

union bfp2 { uint2 u; __bf16 b[4]; };
union bfp4 { uint4 q; bf16x8 v; __bf16 b[8]; };

__device__ __forceinline__ bf16x8 ldw8(const float* __restrict__ p) {
    float4 a = *(const float4*)p;
    float4 b = *(const float4*)(p + 4);
    bf16x8 r;
    r[0] = (__bf16)a.x; r[1] = (__bf16)a.y; r[2] = (__bf16)a.z; r[3] = (__bf16)a.w;
    r[4] = (__bf16)b.x; r[5] = (__bf16)b.y; r[6] = (__bf16)b.z; r[7] = (__bf16)b.w;
    return r;
}

// swizzled LDS fragment read: 256-B rows, 16-B slot XOR (row&7)
__device__ __forceinline__ bf16x8 ldx(const char* base, int row, int kbyte) {
    return *(const bf16x8*)(base + row * 256 + (kbyte ^ ((row & 7) << 4)));
}

// delay lerp into 2 register B-frags (feature g*8+e of sample m) [R16-verified]
#define LERP2(TQT, O1, O2)                                                            \
    {                                                                                 \
        _Pragma("unroll") for (int dl = 0; dl < 2; ++dl) {                            \
            const float tau = dl ? 2.0f : 1.0f;                                       \
            float s = ((TQT) - tau - t0v) * ivd0;                                     \
            s = fminf(fmaxf(s, 0.0f), 255.0f);                                        \
            const int   i0 = (int)s;                                                  \
            const int   i1 = min(i0 + 1, TT - 1);                                     \
            const float w  = s - (float)i0;                                           \
            bfp4 pa, pb, pr;                                                          \
            pa.v = *(const bf16x8*)(hists + (i0 % WSLOTS) * 1280 + m * 80 + g * 16);  \
            pb.v = *(const bf16x8*)(hists + (i1 % WSLOTS) * 1280 + m * 80 + g * 16);  \
            _Pragma("unroll") for (int e = 0; e < 8; ++e) {                           \
                const float va = (float)pa.b[e];                                      \
                pr.b[e] = (__bf16)fmaf(w, (float)pb.b[e] - va, va);                   \
            }                                                                         \
            if (dl == 0) O1 = pr.v; else O2 = pr.v;                                   \
        }                                                                             \
    }

// SegB: L1 hA->hB, one 16-col tile/wave, 2+2 chain + setprio [R17-verified]
#define SEGB()                                                                        \
    {                                                                                 \
        bf16x8 xf[4];                                                                 \
        _Pragma("unroll") for (int kc = 0; kc < 4; ++kc)                              \
            xf[kc] = ldx(hA, m, kc * 64 + g * 16);                                    \
        f32x4 a0 = b1D, cc = {0.f, 0.f, 0.f, 0.f};                                    \
        __builtin_amdgcn_s_setprio(1);                                                \
        a0 = MFMA(W1f[0], xf[0], a0); cc = MFMA(W1f[2], xf[2], cc);                   \
        a0 = MFMA(W1f[1], xf[1], a0); cc = MFMA(W1f[3], xf[3], cc);                   \
        __builtin_amdgcn_s_setprio(0);                                                \
        bfp2 p0;                                                                      \
        _Pragma("unroll") for (int j = 0; j < 4; ++j)                                 \
            p0.b[j] = (__bf16)fmaxf(a0[j] + cc[j], 0.0f);                             \
        *(uint2*)(hB + m * 256 + ((tbB2 + g * 8) ^ sw)) = p0.u;                       \
    }

// SegC: L2 hB-> (h2 store or hsum store), hsum acc in D-layout regs
#define SEGC(COEF, FIRST, STOREH2, DSTBUF)                                            \
    {                                                                                 \
        bf16x8 xf[4];                                                                 \
        _Pragma("unroll") for (int kc = 0; kc < 4; ++kc)                              \
            xf[kc] = ldx(hB, m, kc * 64 + g * 16);                                    \
        f32x4 a0 = b2D, cc = {0.f, 0.f, 0.f, 0.f};                                    \
        __builtin_amdgcn_s_setprio(1);                                                \
        a0 = MFMA(W2f[0], xf[0], a0); cc = MFMA(W2f[2], xf[2], cc);                   \
        a0 = MFMA(W2f[1], xf[1], a0); cc = MFMA(W2f[3], xf[3], cc);                   \
        __builtin_amdgcn_s_setprio(0);                                                \
        f32x4 r;                                                                      \
        _Pragma("unroll") for (int j = 0; j < 4; ++j)                                 \
            r[j] = fmaxf(a0[j] + cc[j], 0.0f);                                        \
        if (FIRST) { _Pragma("unroll") for (int j = 0; j < 4; ++j)                    \
                         hsreg[j] = (COEF) * r[j]; }                                  \
        else       { _Pragma("unroll") for (int j = 0; j < 4; ++j)                    \
                         hsreg[j] = fmaf((COEF), r[j], hsreg[j]); }                   \
        bfp2 ph;                                                                      \
        if (STOREH2) { _Pragma("unroll") for (int j = 0; j < 4; ++j)                  \
                           ph.b[j] = (__bf16)r[j]; }                                  \
        else         { _Pragma("unroll") for (int j = 0; j < 4; ++j)                  \
                           ph.b[j] = (__bf16)hsreg[j]; }                              \
        *(uint2*)((DSTBUF) + m * 256 + ((tbB2 + g * 8) ^ sw)) = ph.u;                 \
    }

// SegA for stages 2/3: fused L0 = relu(u + c*dt*(M*h2 + c0) + W0l*lerp + b0)
#define SEGA23(HIN, CST)                                                              \
    {                                                                                 \
        bf16x8 hf[4];                                                                 \
        _Pragma("unroll") for (int kc = 0; kc < 4; ++kc)                              \
            hf[kc] = ldx(HIN, m, kc * 64 + g * 16);                                   \
        f32x4 ta = {0.f, 0.f, 0.f, 0.f}, tc = ta;                                     \
        __builtin_amdgcn_s_setprio(1);                                                \
        ta = MFMA(Mf[0], hf[0], ta); tc = MFMA(Mf[2], hf[2], tc);                     \
        ta = MFMA(Mf[1], hf[1], ta); tc = MFMA(Mf[3], hf[3], tc);                     \
        __builtin_amdgcn_s_setprio(0);                                                \
        bf16x8 xl1, xl2;                                                              \
        LERP2(fmaf(CST, dt, t), xl1, xl2)                                             \
        f32x4 la = b0D;                                                               \
        __builtin_amdgcn_s_setprio(1);                                                \
        la = MFMA(W0lf[0], xl1, la);                                                  \
        la = MFMA(W0lf[1], xl2, la);                                                  \
        __builtin_amdgcn_s_setprio(0);                                                \
        const float cdt = (CST) * dt;                                                 \
        bfp2 p0;                                                                      \
        _Pragma("unroll") for (int j = 0; j < 4; ++j)                                 \
            p0.b[j] = (__bf16)fmaxf(fmaf(cdt, ta[j] + tc[j] + c0v[j], u[j]) + la[j],  \
                                    0.0f);                                            \
        *(uint2*)(hA + m * 256 + ((tbB2 + g * 8) ^ sw)) = p0.u;                       \
    }

__global__ __launch_bounds__(512, 1) void dde_fu(
    const float* __restrict__ ts, const float* __restrict__ y0,
    const float* __restrict__ W0, const float* __restrict__ b0,
    const float* __restrict__ W1, const float* __restrict__ b1,
    const float* __restrict__ W2, const float* __restrict__ b2,
    const float* __restrict__ W3, const float* __restrict__ b3,
    float* __restrict__ out)
{
    __shared__ __align__(16) char hists[WSLOTS * 1280]; // [slot][m][32bf16], 80-B rows
    __shared__ __align__(16) char hA[16 * 256];
    __shared__ __align__(16) char hB[16 * 256];
    __shared__ __align__(16) char h2a[16 * 256];
    __shared__ __align__(16) char h2b[16 * 256];
    __shared__ __align__(16) char hsb[16 * 256];        // hsum (bf16, swizzled rows)
    __shared__ __align__(16) float ybuf[512];           // y fp32 [sample][feat]
    __shared__ float tsb[TT];
    // ~88 KB LDS, 1 block/CU, 8 waves = 2/SIMD

    const int tid  = threadIdx.x;
    const int lane = tid & 63;
    const int wv   = tid >> 6;        // wave 0..7 -> one 16-col tile of 128-wide layers
    const int m    = lane & 15;       // sample index (B-frag col / D col)
    const int g    = lane >> 4;
    const int tbB2 = wv * 32;
    const int sw   = (m & 7) << 4;
    const int R0   = blockIdx.x * 16;

    for (int idx = tid; idx < WSLOTS * 320; idx += 512) ((unsigned*)hists)[idx] = 0u;
    if (tid < TT) tsb[tid] = ts[tid];

    // ---- weight fragments ----
    bf16x8 W0lf[2], W1f[4], W2f[4], W3f[4], Mf[4];
    {
        const int rw = wv * 16 + m;
        #pragma unroll
        for (int kc = 0; kc < 2; ++kc) W0lf[kc] = ldw8(W0 + rw * 96 + 32 + kc * 32 + g * 8);
        #pragma unroll
        for (int kc = 0; kc < 4; ++kc) W1f[kc] = ldw8(W1 + rw * 128 + kc * 32 + g * 8);
        #pragma unroll
        for (int kc = 0; kc < 4; ++kc) W2f[kc] = ldw8(W2 + rw * 128 + kc * 32 + g * 8);
        const int rw3 = (wv & 1) * 16 + m;   // only waves 0/1 use W3f
        #pragma unroll
        for (int kc = 0; kc < 4; ++kc) W3f[kc] = ldw8(W3 + rw3 * 128 + kc * 32 + g * 8);
    }
    // ---- M = W0y * W3 fragments (bf16), computed on device ----
    {
        float w0y[32];
        const float* w0r = W0 + (wv * 16 + m) * 96;
        #pragma unroll
        for (int d = 0; d < 32; ++d) w0y[d] = w0r[d];
        #pragma unroll
        for (int kc = 0; kc < 4; ++kc) {
            bf16x8 f;
            #pragma unroll
            for (int e = 0; e < 8; ++e) {
                const int h = kc * 32 + g * 8 + e;
                float acc = 0.f;
                #pragma unroll
                for (int d = 0; d < 32; ++d) acc = fmaf(w0y[d], W3[d * 128 + h], acc);
                f[e] = (__bf16)acc;
            }
            Mf[kc] = f;
        }
    }
    // ---- biases (D-layout), c0 = W0y*b3, u = W0y*y0 ----
    f32x4 b0D = *(const f32x4*)(b0 + wv * 16 + g * 4);
    f32x4 b1D = *(const f32x4*)(b1 + wv * 16 + g * 4);
    f32x4 b2D = *(const f32x4*)(b2 + wv * 16 + g * 4);
    f32x4 b3D = *(const f32x4*)(b3 + (wv & 1) * 16 + g * 4);
    f32x4 c0v, u;
    {
        const float* yr = y0 + (R0 + m) * DATA;
        #pragma unroll
        for (int j = 0; j < 4; ++j) {
            const float* w0r = W0 + (wv * 16 + g * 4 + j) * 96;
            float a = 0.f, uu = 0.f;
            #pragma unroll
            for (int d = 0; d < 32; ++d) {
                a  = fmaf(w0r[d], b3[d], a);
                uu = fmaf(w0r[d], yr[d], uu);
            }
            c0v[j] = a; u[j] = uu;
        }
    }
    // ---- y (waves 0/1 only; D-layout: sample m, feature wv*16+4g+j) ----
    f32x4 y;
    #pragma unroll
    for (int j = 0; j < 4; ++j)
        y[j] = y0[(R0 + m) * DATA + (wv & 1) * 16 + g * 4 + j];

    __syncthreads();   // hist zero complete

    if (wv == 0) {     // hist slot 0 + out[0] (B-layout rows, exact fp32 out)
        float4 v0 = *(const float4*)(y0 + (R0 + m) * DATA + g * 8);
        float4 v1 = *(const float4*)(y0 + (R0 + m) * DATA + g * 8 + 4);
        bfp4 p;
        p.b[0] = (__bf16)v0.x; p.b[1] = (__bf16)v0.y;
        p.b[2] = (__bf16)v0.z; p.b[3] = (__bf16)v0.w;
        p.b[4] = (__bf16)v1.x; p.b[5] = (__bf16)v1.y;
        p.b[6] = (__bf16)v1.z; p.b[7] = (__bf16)v1.w;
        *(bf16x8*)(hists + m * 80 + g * 16) = p.v;
        *(float4*)(out + (R0 + m) * DATA + g * 8) = v0;
        *(float4*)(out + (R0 + m) * DATA + g * 8 + 4) = v1;
    }
    if (blockIdx.x == 0 && tid == 0)
        out[(size_t)TT * BATCH * DATA] = 255.0f;   // tuple output 1: int32(T-1)
    __syncthreads();

    const float t0v  = tsb[0];
    const float ivd0 = 1.0f / (tsb[1] - tsb[0]);

    #pragma unroll 1
    for (int i = 0; i < TT - 1; ++i) {
        const float t  = tsb[i];
        const float dt = tsb[i + 1] - t;
        f32x4 hsreg;

        // ================= stage 1 =================
        {   // SegA: [i>0: u/y update from hsum] + L0 = relu(u + W0l*lerp + b0)
            if (i > 0) {
                const float dtp = t - tsb[i - 1];
                bf16x8 hs[4];
                #pragma unroll
                for (int kc = 0; kc < 4; ++kc) hs[kc] = ldx(hsb, m, kc * 64 + g * 16);
                f32x4 ta = {0.f, 0.f, 0.f, 0.f}, tc = ta;
                __builtin_amdgcn_s_setprio(1);
                ta = MFMA(Mf[0], hs[0], ta); tc = MFMA(Mf[2], hs[2], tc);
                ta = MFMA(Mf[1], hs[1], ta); tc = MFMA(Mf[3], hs[3], tc);
                __builtin_amdgcn_s_setprio(0);
                #pragma unroll
                for (int j = 0; j < 4; ++j)
                    u[j] = fmaf(dtp, ta[j] + tc[j] + c0v[j], u[j]);
                if (wv < 2) {
                    f32x4 ya = {0.f, 0.f, 0.f, 0.f}, yc = ya;
                    __builtin_amdgcn_s_setprio(1);
                    ya = MFMA(W3f[0], hs[0], ya); yc = MFMA(W3f[2], hs[2], yc);
                    ya = MFMA(W3f[1], hs[1], ya); yc = MFMA(W3f[3], hs[3], yc);
                    __builtin_amdgcn_s_setprio(0);
                    #pragma unroll
                    for (int j = 0; j < 4; ++j) {
                        y[j] = fmaf(dtp, ya[j] + yc[j] + b3D[j], y[j]);
                        *(__bf16*)(hists + (i % WSLOTS) * 1280 + m * 80
                                   + wv * 32 + g * 8 + 2 * j) = (__bf16)y[j];
                        ybuf[m * 32 + wv * 16 + g * 4 + j] = y[j];
                    }
                }
            }
            bf16x8 xl1, xl2;
            LERP2(t, xl1, xl2)
            f32x4 la = b0D;
            __builtin_amdgcn_s_setprio(1);
            la = MFMA(W0lf[0], xl1, la);
            la = MFMA(W0lf[1], xl2, la);
            __builtin_amdgcn_s_setprio(0);
            bfp2 p0;
            #pragma unroll
            for (int j = 0; j < 4; ++j)
                p0.b[j] = (__bf16)fmaxf(u[j] + la[j], 0.0f);
            *(uint2*)(hA + m * 256 + ((tbB2 + g * 8) ^ sw)) = p0.u;
        }
        __syncthreads();
        SEGB()
        __syncthreads();
        SEGC(2.0f / 9.0f, 1, 1, h2a)
        if (i > 0 && wv < 2) {   // coalesced out[i] from ybuf (written 2 barriers ago)
            const int L = wv * 64 + lane;
            float4 yv = *(const float4*)(ybuf + L * 4);
            *(float4*)(out + (size_t)i * BATCH * DATA
                       + (R0 + (L >> 3)) * DATA + (L & 7) * 4) = yv;
        }
        __syncthreads();
        // ================= stage 2 =================
        SEGA23(h2a, 0.5f)
        __syncthreads();
        SEGB()
        __syncthreads();
        SEGC(1.0f / 3.0f, 0, 1, h2b)
        __syncthreads();
        // ================= stage 3 =================
        SEGA23(h2b, 0.75f)
        __syncthreads();
        SEGB()
        __syncthreads();
        SEGC(4.0f / 9.0f, 0, 0, hsb)   // stores hsum (h2_3 itself not needed)
        __syncthreads();
        // Hazards: hA written SegA(s), read SegB(s), rewritten >=2 barriers later.
        // hB likewise. h2a: W stage1-SegC, R stage2-SegA (1 bar), next W >=5 bars.
        // h2b likewise. hsb: W stage3-SegC, R next-step stage1-SegA (1 bar), next
        // W 8 bars after read. ybuf: W stage1-SegA, R stage1-SegC (2 bars), next
        // W >=7 bars. hist slot i: W stage1-SegA(i), first lerp read >=24 steps.
    }

    // ---- epilogue: y_255 and out[255] ----
    if (wv < 2) {
        const float dtp = tsb[TT - 1] - tsb[TT - 2];
        bf16x8 hs[4];
        #pragma unroll
        for (int kc = 0; kc < 4; ++kc) hs[kc] = ldx(hsb, m, kc * 64 + g * 16);
        f32x4 ya = {0.f, 0.f, 0.f, 0.f}, yc = ya;
        ya = MFMA(W3f[0], hs[0], ya); yc = MFMA(W3f[2], hs[2], yc);
        ya = MFMA(W3f[1], hs[1], ya); yc = MFMA(W3f[3], hs[3], yc);
        #pragma unroll
        for (int j = 0; j < 4; ++j) {
            y[j] = fmaf(dtp, ya[j] + yc[j] + b3D[j], y[j]);
            ybuf[m * 32 + (wv & 1) * 16 + g * 4 + j] = y[j];
        }
    }
    __syncthreads();
    if (wv < 2) {
        const int L = wv * 64 + lane;
        float4 yv = *(const float4*)(ybuf + L * 4);
        *(float4*)(out + (size_t)(TT - 1) * BATCH * DATA
                   + (R0 + (L >> 3)) * DATA + (L & 7) * 4) = yv;
    }
}

extern "C" void kernel_launch(void* const* d_in, const int* in_sizes, int n_in,
                              void* d_out, int out_size, void* d_ws, size_t ws_size,
                              hipStream_t stream) {
    const float* ts = (const float*)d_in[0];
    const float* y0 = (const float*)d_in[1];
    const float* W0 = (const float*)d_in[2];
    const float* b0 = (const float*)d_in[3];
    const float* W1 = (const float*)d_in[4];
    const float* b1 = (const float*)d_in[5];
    const float* W2 = (const float*)d_in[6];
    const float* b2 = (const float*)d_in[7];
    const float* W3 = (const float*)d_in[8];
    const float* b3 = (const float*)d_in[9];

    dde_fu<<<dim3(BATCH / 16), dim3(512), 0, stream>>>(
        ts, y0, W0, b0, W1, b1, W2, b2, W3, b3, (float*)d_out);
}

// Round 19
// 824.243 us; speedup vs baseline: 1.0215x; 1.0215x over previous
//
#include <hip/hip_runtime.h>

#define TT 256
#define BATCH 2048
#define DATA 32
#define WSLOTS 52

typedef __bf16 bf16x8 __attribute__((ext_vector_type(8)));
typedef float f32x4 __attribute__((ext_vector_type(4)));

#define MFMA(A, B, C) __builtin_amdgcn_mfma_f32_16x16x32_bf16((A), (B), (C), 0, 0, 0)

union bfp2 { uint2 u; __bf16 b[4]; };
union bfp4 { uint4 q; bf16x8 v; __bf16 b[8]; };

__device__ __forceinline__ bf16x8 ldw8(const float* __restrict__ p) {
    float4 a = *(const float4*)p;
    float4 b = *(const float4*)(p + 4);
    bf16x8 r;
    r[0] = (__bf16)a.x; r[1] = (__bf16)a.y; r[2] = (__bf16)a.z; r[3] = (__bf16)a.w;
    r[4] = (__bf16)b.x; r[5] = (__bf16)b.y; r[6] = (__bf16)b.z; r[7] = (__bf16)b.w;
    return r;
}

// swizzled LDS fragment read: 256-B rows, 16-B slot XOR (row&7)
__device__ __forceinline__ bf16x8 ldx(const char* base, int row, int kbyte) {
    return *(const bf16x8*)(base + row * 256 + (kbyte ^ ((row & 7) << 4)));
}

// delay lerp into 2 register B-frags (feature g*8+e of sample m) [R16/R18-verified]
#define LERP2(TQT, O1, O2)                                                            \
    {                                                                                 \
        _Pragma("unroll") for (int dl = 0; dl < 2; ++dl) {                            \
            const float tau = dl ? 2.0f : 1.0f;                                       \
            float s = ((TQT) - tau - t0v) * ivd0;                                     \
            s = fminf(fmaxf(s, 0.0f), 255.0f);                                        \
            const int   i0 = (int)s;                                                  \
            const int   i1 = min(i0 + 1, TT - 1);                                     \
            const float w  = s - (float)i0;                                           \
            bfp4 pa, pb, pr;                                                          \
            pa.v = *(const bf16x8*)(hists + (i0 % WSLOTS) * 1280 + m * 80 + g * 16);  \
            pb.v = *(const bf16x8*)(hists + (i1 % WSLOTS) * 1280 + m * 80 + g * 16);  \
            _Pragma("unroll") for (int e = 0; e < 8; ++e) {                           \
                const float va = (float)pa.b[e];                                      \
                pr.b[e] = (__bf16)fmaf(w, (float)pb.b[e] - va, va);                   \
            }                                                                         \
            if (dl == 0) O1 = pr.v; else O2 = pr.v;                                   \
        }                                                                             \
    }

// SegB: L1 hA->hB + lerp prefetch into registers (hist reads hide under MFMA)
#define SEGB_PF(TQ2, O1, O2)                                                          \
    {                                                                                 \
        bf16x8 xf[4];                                                                 \
        _Pragma("unroll") for (int kc = 0; kc < 4; ++kc)                              \
            xf[kc] = ldx(hA, m, kc * 64 + g * 16);                                    \
        f32x4 a0 = b1D, cc = {0.f, 0.f, 0.f, 0.f};                                    \
        __builtin_amdgcn_s_setprio(1);                                                \
        a0 = MFMA(W1f[0], xf[0], a0); cc = MFMA(W1f[2], xf[2], cc);                   \
        a0 = MFMA(W1f[1], xf[1], a0); cc = MFMA(W1f[3], xf[3], cc);                   \
        __builtin_amdgcn_s_setprio(0);                                                \
        LERP2(TQ2, O1, O2)                                                            \
        bfp2 p0;                                                                      \
        _Pragma("unroll") for (int j = 0; j < 4; ++j)                                 \
            p0.b[j] = (__bf16)fmaxf(a0[j] + cc[j], 0.0f);                             \
        *(uint2*)(hB + m * 256 + ((tbB2 + g * 8) ^ sw)) = p0.u;                       \
    }

// SegC: L2 hB -> (h2 store or hsum store), hsum acc in D-layout regs [R18]
#define SEGC(COEF, FIRST, STOREH2, DSTBUF)                                            \
    {                                                                                 \
        bf16x8 xf[4];                                                                 \
        _Pragma("unroll") for (int kc = 0; kc < 4; ++kc)                              \
            xf[kc] = ldx(hB, m, kc * 64 + g * 16);                                    \
        f32x4 a0 = b2D, cc = {0.f, 0.f, 0.f, 0.f};                                    \
        __builtin_amdgcn_s_setprio(1);                                                \
        a0 = MFMA(W2f[0], xf[0], a0); cc = MFMA(W2f[2], xf[2], cc);                   \
        a0 = MFMA(W2f[1], xf[1], a0); cc = MFMA(W2f[3], xf[3], cc);                   \
        __builtin_amdgcn_s_setprio(0);                                                \
        f32x4 r;                                                                      \
        _Pragma("unroll") for (int j = 0; j < 4; ++j)                                 \
            r[j] = fmaxf(a0[j] + cc[j], 0.0f);                                        \
        if (FIRST) { _Pragma("unroll") for (int j = 0; j < 4; ++j)                    \
                         hsreg[j] = (COEF) * r[j]; }                                  \
        else       { _Pragma("unroll") for (int j = 0; j < 4; ++j)                    \
                         hsreg[j] = fmaf((COEF), r[j], hsreg[j]); }                   \
        bfp2 ph;                                                                      \
        if (STOREH2) { _Pragma("unroll") for (int j = 0; j < 4; ++j)                  \
                           ph.b[j] = (__bf16)r[j]; }                                  \
        else         { _Pragma("unroll") for (int j = 0; j < 4; ++j)                  \
                           ph.b[j] = (__bf16)hsreg[j]; }                              \
        *(uint2*)((DSTBUF) + m * 256 + ((tbB2 + g * 8) ^ sw)) = ph.u;                 \
    }

// SegA stages 2/3: fused L0 = relu(u + c*dt*(M*h2 + c0) + W0l*lerp + b0),
// lerp fragments already in registers (prefetched previous SegB) -> thin segment.
#define SEGA_F(HIN, CST, XL1, XL2)                                                    \
    {                                                                                 \
        bf16x8 hf[4];                                                                 \
        _Pragma("unroll") for (int kc = 0; kc < 4; ++kc)                              \
            hf[kc] = ldx(HIN, m, kc * 64 + g * 16);                                   \
        f32x4 la = b0D;                                                               \
        f32x4 ta = {0.f, 0.f, 0.f, 0.f}, tc = ta;                                     \
        __builtin_amdgcn_s_setprio(1);                                                \
        la = MFMA(W0lf[0], XL1, la);          /* operands ready: issue first */       \
        la = MFMA(W0lf[1], XL2, la);                                                  \
        ta = MFMA(Mf[0], hf[0], ta); tc = MFMA(Mf[2], hf[2], tc);                     \
        ta = MFMA(Mf[1], hf[1], ta); tc = MFMA(Mf[3], hf[3], tc);                     \
        __builtin_amdgcn_s_setprio(0);                                                \
        const float cdt = (CST) * dt;                                                 \
        bfp2 p0;                                                                      \
        _Pragma("unroll") for (int j = 0; j < 4; ++j)                                 \
            p0.b[j] = (__bf16)fmaxf(fmaf(cdt, ta[j] + tc[j] + c0v[j], u[j]) + la[j],  \
                                    0.0f);                                            \
        *(uint2*)(hA + m * 256 + ((tbB2 + g * 8) ^ sw)) = p0.u;                       \
    }

__global__ __launch_bounds__(512, 1) void dde_f2(
    const float* __restrict__ ts, const float* __restrict__ y0,
    const float* __restrict__ W0, const float* __restrict__ b0,
    const float* __restrict__ W1, const float* __restrict__ b1,
    const float* __restrict__ W2, const float* __restrict__ b2,
    const float* __restrict__ W3, const float* __restrict__ b3,
    float* __restrict__ out)
{
    __shared__ __align__(16) char hists[WSLOTS * 1280]; // [slot][m][32bf16], 80-B rows
    __shared__ __align__(16) char Mlds[128 * 256];      // M = W0y*W3 bf16, swizzled
    __shared__ __align__(16) char hA[16 * 256];
    __shared__ __align__(16) char hB[16 * 256];
    __shared__ __align__(16) char h2a[16 * 256];
    __shared__ __align__(16) char h2b[16 * 256];
    __shared__ __align__(16) char hsb[16 * 256];        // hsum bf16
    __shared__ __align__(16) float ybuf[512];           // y fp32 [sample][feat]
    __shared__ float tsb[TT];
    // ~121 KB LDS, 1 block/CU, 8 waves = 2/SIMD

    const int tid  = threadIdx.x;
    const int lane = tid & 63;
    const int wv   = tid >> 6;        // wave 0..7 -> one 16-col tile
    const int m    = lane & 15;       // sample index
    const int g    = lane >> 4;
    const int tbB2 = wv * 32;
    const int sw   = (m & 7) << 4;
    const int R0   = blockIdx.x * 16;

    for (int idx = tid; idx < WSLOTS * 320; idx += 512) ((unsigned*)hists)[idx] = 0u;
    if (tid < TT) tsb[tid] = ts[tid];

    // ---- weight fragments ----
    bf16x8 W0lf[2], W1f[4], W2f[4], W3f[4];
    {
        const int rw = wv * 16 + m;
        #pragma unroll
        for (int kc = 0; kc < 2; ++kc) W0lf[kc] = ldw8(W0 + rw * 96 + 32 + kc * 32 + g * 8);
        #pragma unroll
        for (int kc = 0; kc < 4; ++kc) W1f[kc] = ldw8(W1 + rw * 128 + kc * 32 + g * 8);
        #pragma unroll
        for (int kc = 0; kc < 4; ++kc) W2f[kc] = ldw8(W2 + rw * 128 + kc * 32 + g * 8);
        const int rw3 = (wv & 1) * 16 + m;   // only waves 0/1 use W3f
        #pragma unroll
        for (int kc = 0; kc < 4; ++kc) W3f[kc] = ldw8(W3 + rw3 * 128 + kc * 32 + g * 8);
    }
    // ---- M = W0y*W3 via MFMA (one 16x16x32 per 16-col tile of M's row-slice) ----
    {
        bf16x8 Af = ldw8(W0 + (wv * 16 + m) * 96 + g * 8);   // A[m][k=g*8+e]
        #pragma unroll
        for (int ht = 0; ht < 8; ++ht) {
            bf16x8 Bf;
            #pragma unroll
            for (int e = 0; e < 8; ++e)                      // B[k=g*8+e][n=ht*16+m]
                Bf[e] = (__bf16)W3[(g * 8 + e) * 128 + ht * 16 + m];
            f32x4 d = {0.f, 0.f, 0.f, 0.f};
            d = MFMA(Af, Bf, d);
            #pragma unroll
            for (int j = 0; j < 4; ++j) {                    // D: row g*4+j, col m
                const int r = wv * 16 + g * 4 + j;
                *(__bf16*)(Mlds + r * 256 + (((ht * 16 + m) * 2) ^ ((r & 7) << 4)))
                    = (__bf16)d[j];
            }
        }
    }
    // ---- biases (D-layout), c0 = W0y*b3, u = W0y*y0 ----
    f32x4 b0D = *(const f32x4*)(b0 + wv * 16 + g * 4);
    f32x4 b1D = *(const f32x4*)(b1 + wv * 16 + g * 4);
    f32x4 b2D = *(const f32x4*)(b2 + wv * 16 + g * 4);
    f32x4 b3D = *(const f32x4*)(b3 + (wv & 1) * 16 + g * 4);
    f32x4 c0v, u;
    {
        const float* yr = y0 + (R0 + m) * DATA;
        #pragma unroll
        for (int j = 0; j < 4; ++j) {
            const float* w0r = W0 + (wv * 16 + g * 4 + j) * 96;
            float a = 0.f, uu = 0.f;
            #pragma unroll
            for (int d = 0; d < 32; ++d) {
                a  = fmaf(w0r[d], b3[d], a);
                uu = fmaf(w0r[d], yr[d], uu);
            }
            c0v[j] = a; u[j] = uu;
        }
    }
    f32x4 y;
    #pragma unroll
    for (int j = 0; j < 4; ++j)
        y[j] = y0[(R0 + m) * DATA + (wv & 1) * 16 + g * 4 + j];

    __syncthreads();   // hist zero + Mlds writes complete

    bf16x8 Mf[4];
    #pragma unroll
    for (int kc = 0; kc < 4; ++kc) Mf[kc] = ldx(Mlds, wv * 16 + m, kc * 64 + g * 16);

    if (wv == 0) {     // hist slot 0 + out[0] (exact fp32)
        float4 v0 = *(const float4*)(y0 + (R0 + m) * DATA + g * 8);
        float4 v1 = *(const float4*)(y0 + (R0 + m) * DATA + g * 8 + 4);
        bfp4 p;
        p.b[0] = (__bf16)v0.x; p.b[1] = (__bf16)v0.y;
        p.b[2] = (__bf16)v0.z; p.b[3] = (__bf16)v0.w;
        p.b[4] = (__bf16)v1.x; p.b[5] = (__bf16)v1.y;
        p.b[6] = (__bf16)v1.z; p.b[7] = (__bf16)v1.w;
        *(bf16x8*)(hists + m * 80 + g * 16) = p.v;
        *(float4*)(out + (R0 + m) * DATA + g * 8) = v0;
        *(float4*)(out + (R0 + m) * DATA + g * 8 + 4) = v1;
    }
    if (blockIdx.x == 0 && tid == 0)
        out[(size_t)TT * BATCH * DATA] = 255.0f;   // tuple output 1: int32(T-1)
    __syncthreads();   // hist slot 0 visible

    const float t0v  = tsb[0];
    const float ivd0 = 1.0f / (tsb[1] - tsb[0]);

    bf16x8 xl1a, xl1b, xl2a, xl2b, xl3a, xl3b;
    LERP2(t0v, xl1a, xl1b)     // stage-1 lerp for step 0

    #pragma unroll 1
    for (int i = 0; i < TT - 1; ++i) {
        const float t  = tsb[i];
        const float tn = tsb[i + 1];
        const float dt = tn - t;
        f32x4 hsreg;

        // ===== stage 1 =====
        {   // SegA: [i>0: u/y update from hsum] + L0 = relu(u + W0l*lerp1 + b0)
            if (i > 0) {
                const float dtp = t - tsb[i - 1];
                bf16x8 hs[4];
                #pragma unroll
                for (int kc = 0; kc < 4; ++kc) hs[kc] = ldx(hsb, m, kc * 64 + g * 16);
                f32x4 ta = {0.f, 0.f, 0.f, 0.f}, tc = ta;
                __builtin_amdgcn_s_setprio(1);
                ta = MFMA(Mf[0], hs[0], ta); tc = MFMA(Mf[2], hs[2], tc);
                ta = MFMA(Mf[1], hs[1], ta); tc = MFMA(Mf[3], hs[3], tc);
                __builtin_amdgcn_s_setprio(0);
                #pragma unroll
                for (int j = 0; j < 4; ++j)
                    u[j] = fmaf(dtp, ta[j] + tc[j] + c0v[j], u[j]);
                if (wv < 2) {
                    f32x4 ya = {0.f, 0.f, 0.f, 0.f}, yc = ya;
                    __builtin_amdgcn_s_setprio(1);
                    ya = MFMA(W3f[0], hs[0], ya); yc = MFMA(W3f[2], hs[2], yc);
                    ya = MFMA(W3f[1], hs[1], ya); yc = MFMA(W3f[3], hs[3], yc);
                    __builtin_amdgcn_s_setprio(0);
                    #pragma unroll
                    for (int j = 0; j < 4; ++j) {
                        y[j] = fmaf(dtp, ya[j] + yc[j] + b3D[j], y[j]);
                        *(__bf16*)(hists + (i % WSLOTS) * 1280 + m * 80
                                   + wv * 32 + g * 8 + 2 * j) = (__bf16)y[j];
                        ybuf[m * 32 + wv * 16 + g * 4 + j] = y[j];
                    }
                }
            }
            f32x4 la = b0D;
            __builtin_amdgcn_s_setprio(1);
            la = MFMA(W0lf[0], xl1a, la);
            la = MFMA(W0lf[1], xl1b, la);
            __builtin_amdgcn_s_setprio(0);
            bfp2 p0;
            #pragma unroll
            for (int j = 0; j < 4; ++j)
                p0.b[j] = (__bf16)fmaxf(u[j] + la[j], 0.0f);
            *(uint2*)(hA + m * 256 + ((tbB2 + g * 8) ^ sw)) = p0.u;
        }
        __syncthreads();
        SEGB_PF(fmaf(0.5f, dt, t), xl2a, xl2b)
        __syncthreads();
        SEGC(2.0f / 9.0f, 1, 1, h2a)
        if (i > 0 && wv < 2) {   // coalesced out[i] from ybuf (2 barriers after write)
            const int L = wv * 64 + lane;
            float4 yv = *(const float4*)(ybuf + L * 4);
            *(float4*)(out + (size_t)i * BATCH * DATA
                       + (R0 + (L >> 3)) * DATA + (L & 7) * 4) = yv;
        }
        __syncthreads();
        // ===== stage 2 =====
        SEGA_F(h2a, 0.5f, xl2a, xl2b)
        __syncthreads();
        SEGB_PF(fmaf(0.75f, dt, t), xl3a, xl3b)
        __syncthreads();
        SEGC(1.0f / 3.0f, 0, 1, h2b)
        __syncthreads();
        // ===== stage 3 =====
        SEGA_F(h2b, 0.75f, xl3a, xl3b)
        __syncthreads();
        SEGB_PF(tn, xl1a, xl1b)        // next step's stage-1 lerp (slots <= i-24)
        __syncthreads();
        SEGC(4.0f / 9.0f, 0, 0, hsb)   // stores hsum
        __syncthreads();
        // Hazards: hA W SegA / R SegB, next W >=2 bars after R. hB W SegB / R SegC.
        // h2a W S1.SegC / R S2.SegA (1 bar), next W >=6 bars. h2b likewise.
        // hsb W S3.SegC / R next S1.SegA (1 bar), next W 8 bars after R.
        // ybuf W S1.SegA / R S1.SegC (2 bars). hist slot i W S1.SegA; lerp
        // prefetches read slots <= cur-24 (disjoint, visible). Mlds read-only.
    }

    // ---- epilogue: y_255 and out[255] ----
    if (wv < 2) {
        const float dtp = tsb[TT - 1] - tsb[TT - 2];
        bf16x8 hs[4];
        #pragma unroll
        for (int kc = 0; kc < 4; ++kc) hs[kc] = ldx(hsb, m, kc * 64 + g * 16);
        f32x4 ya = {0.f, 0.f, 0.f, 0.f}, yc = ya;
        ya = MFMA(W3f[0], hs[0], ya); yc = MFMA(W3f[2], hs[2], yc);
        ya = MFMA(W3f[1], hs[1], ya); yc = MFMA(W3f[3], hs[3], yc);
        #pragma unroll
        for (int j = 0; j < 4; ++j) {
            y[j] = fmaf(dtp, ya[j] + yc[j] + b3D[j], y[j]);
            ybuf[m * 32 + (wv & 1) * 16 + g * 4 + j] = y[j];
        }
    }
    __syncthreads();
    if (wv < 2) {
        const int L = wv * 64 + lane;
        float4 yv = *(const float4*)(ybuf + L * 4);
        *(float4*)(out + (size_t)(TT - 1) * BATCH * DATA
                   + (R0 + (L >> 3)) * DATA + (L & 7) * 4) = yv;
    }
}

extern "C" void kernel_launch(void* const* d_in, const int* in_sizes, int n_in,
                              void* d_out, int out_size, void* d_ws, size_t ws_size,
                              hipStream_t stream) {
    const float* ts = (const float*)d_in[0];
    const float* y0 = (const float*)d_in[1];
    const float* W0 = (const float*)d_in[2];
    const float* b0 = (const float*)d_in[3];
    const float* W1 = (const float*)d_in[4];
    const float* b1 = (const float*)d_in[5];
    const float* W2 = (const float*)d_in[6];
    const float* b2 = (const float*)d_in[7];
    const float* W3 = (const float*)d_in[8];
    const float* b3 = (const float*)d_in[9];

    dde_f2<<<dim3(BATCH / 16), dim3(512), 0, stream>>>(
        ts, y0, W0, b0, W1, b1, W2, b2, W3, b3, (float*)d_out);
}

// Round 20
// 699.138 us; speedup vs baseline: 1.2043x; 1.1789x over previous
//
#include <hip/hip_runtime.h>

#define TT 256
#define BATCH 2048
#define DATA 32
#define WSLOTS 52

typedef __bf16 bf16x8 __attribute__((ext_vector_type(8)));
typedef float f32x4 __attribute__((ext_vector_type(4)));

#define MFMA(A, B, C) __builtin_amdgcn_mfma_f32_16x16x32_bf16((A), (B), (C), 0, 0, 0)

union bfp2 { uint2 u; __bf16 b[4]; };
union bfp4 { uint4 q; bf16x8 v; __bf16 b[8]; };

// fp32 x8 (global) -> bf16x8 fragment (prologue only)
__device__ __forceinline__ bf16x8 ldw8(const float* __restrict__ p) {
    float4 a = *(const float4*)p;
    float4 b = *(const float4*)(p + 4);
    bf16x8 r;
    r[0] = (__bf16)a.x; r[1] = (__bf16)a.y; r[2] = (__bf16)a.z; r[3] = (__bf16)a.w;
    r[4] = (__bf16)b.x; r[5] = (__bf16)b.y; r[6] = (__bf16)b.z; r[7] = (__bf16)b.w;
    return r;
}

// swizzled LDS fragment read for hA/hB: 256-B rows, 16-B slot XOR (row&7)
__device__ __forceinline__ bf16x8 ldx(const char* base, int row, int kbyte) {
    return *(const bf16x8*)(base + row * 256 + (kbyte ^ ((row & 7) << 4)));
}

// One 16-col output tile; 2+2 chain + setprio [R17-verified]
#define HID1(WF, KC, SRC, DST, BI)                                                    \
    {                                                                                 \
        bf16x8 xf[4];                                                                 \
        _Pragma("unroll") for (int kc = 0; kc < (KC); ++kc)                           \
            xf[kc] = ldx(SRC, m, kc * 64 + g * 16);                                   \
        f32x4 a0 = BI, c0 = {0.f, 0.f, 0.f, 0.f};                                     \
        __builtin_amdgcn_s_setprio(1);                                                \
        _Pragma("unroll") for (int kc = 0; kc < (KC); ++kc) {                         \
            if (kc < 2) a0 = MFMA(WF[kc], xf[kc], a0);                                \
            else        c0 = MFMA(WF[kc], xf[kc], c0);                                \
        }                                                                             \
        __builtin_amdgcn_s_setprio(0);                                                \
        a0 = a0 + c0;                                                                 \
        bfp2 p0;                                                                      \
        _Pragma("unroll") for (int j = 0; j < 4; ++j)                                 \
            p0.b[j] = (__bf16)fmaxf(a0[j], 0.0f);                                     \
        *(uint2*)((DST) + m * 256 + ((tbB2 + g * 8) ^ sw)) = p0.u;                    \
    }

// waves 2/3 (dl = wv-2): lerp columns for time TQT -> XDST dl-region. [R17]
#define PRELERP(TQT, XDST)                                                            \
    {                                                                                 \
        const int   dl  = wv - 2;                                                     \
        const float tau = dl ? 2.0f : 1.0f;                                           \
        float s = ((TQT) - tau - t0v) * ivd0;                                         \
        s = fminf(fmaxf(s, 0.0f), 255.0f);                                            \
        const int   i0 = (int)s;                                                      \
        const int   i1 = min(i0 + 1, TT - 1);                                         \
        const float w  = s - (float)i0;                                               \
        bfp4 pa, pb, pr;                                                              \
        pa.v = *(const bf16x8*)(hists + (i0 % WSLOTS) * 1280 + m * 80 + g * 16);      \
        pb.v = *(const bf16x8*)(hists + (i1 % WSLOTS) * 1280 + m * 80 + g * 16);      \
        _Pragma("unroll") for (int e = 0; e < 8; ++e) {                               \
            const float va = (float)pa.b[e];                                          \
            pr.b[e] = (__bf16)fmaf(w, (float)pb.b[e] - va, va);                       \
        }                                                                             \
        *(bf16x8*)((XDST) + dl * 1280 + m * 80 + g * 16) = pr.v;                      \
    }

// One RK stage: 4 segments/barriers; 8 waves (2/SIMD). [R17 base]
// NEW vs R17: XNXT's two lerp fragments are prefetched into registers at the
// top of SegD (XNXT written >=4 barriers ago -> safe), and the next SegA issues
// its W0l MFMAs on those registers FIRST, overlapping the kbuf read latency.
#define DO_STAGE(USEK, CST, KP, KD, XL1, XL2, XDST, TQT, XNXT, NL1, NL2)              \
    {                                                                                 \
        /* SegA: L0; lerp frags already in registers (XL1/XL2) */                     \
        f32x4 a0 = bias0, c0 = {0.f, 0.f, 0.f, 0.f};                                  \
        __builtin_amdgcn_s_setprio(1);                                                \
        a0 = MFMA(W0f[1], XL1, a0);          /* operands ready: issue first */        \
        c0 = MFMA(W0f[2], XL2, c0);                                                   \
        __builtin_amdgcn_s_setprio(0);                                                \
        bfp4 xf0;                                                                     \
        _Pragma("unroll") for (int e = 0; e < 8; ++e)                                 \
            xf0.b[e] = (__bf16)((USEK) ? fmaf((CST) * dt, KP[e], y[e]) : y[e]);       \
        __builtin_amdgcn_s_setprio(1);                                                \
        a0 = MFMA(W0f[0], xf0.v, a0);                                                 \
        __builtin_amdgcn_s_setprio(0);                                                \
        a0 = a0 + c0;                                                                 \
        bfp2 p0;                                                                      \
        _Pragma("unroll") for (int j = 0; j < 4; ++j)                                 \
            p0.b[j] = (__bf16)fmaxf(a0[j], 0.0f);                                     \
        *(uint2*)(hA + m * 256 + ((tbB2 + g * 8) ^ sw)) = p0.u;                       \
        __syncthreads();                                                              \
        HID1(W1f, 4, hA, hB, bias1)                                                   \
        __syncthreads();                                                              \
        HID1(W2f, 4, hB, hA, bias2)                                                   \
        __syncthreads();                                                              \
        /* SegD: prefetch next stage's lerp frags (>=4-barrier-old buffer) */         \
        NL1 = *(const bf16x8*)((XNXT) + m * 80 + g * 16);                             \
        NL2 = *(const bf16x8*)((XNXT) + 1280 + m * 80 + g * 16);                      \
        if (wv < 2) {   /* L3 -> kbuf (D-layout, swizzled slots) */                   \
            bf16x8 xf[4];                                                             \
            _Pragma("unroll") for (int kc = 0; kc < 4; ++kc)                          \
                xf[kc] = ldx(hA, m, kc * 64 + g * 16);                                \
            f32x4 a3 = bias3, c3 = {0.f, 0.f, 0.f, 0.f};                              \
            __builtin_amdgcn_s_setprio(1);                                            \
            a3 = MFMA(W3f[0], xf[0], a3);                                             \
            c3 = MFMA(W3f[2], xf[2], c3);                                             \
            a3 = MFMA(W3f[1], xf[1], a3);                                             \
            c3 = MFMA(W3f[3], xf[3], c3);                                             \
            __builtin_amdgcn_s_setprio(0);                                            \
            a3 = a3 + c3;                                                             \
            *(f32x4*)(kbuf + m * 128 + (((wv * 4 + g) ^ (m & 7)) << 4)) = a3;         \
        } else if (wv < 4) {                                                          \
            PRELERP(TQT, XDST)                                                        \
        }                                                                             \
        __syncthreads();                                                              \
        {   /* k broadcast: all waves -> B-layout registers */                        \
            f32x4 q0 = *(const f32x4*)(kbuf + m * 128 + (((2 * g) ^ (m & 7)) << 4));  \
            f32x4 q1 = *(const f32x4*)(kbuf + m * 128 + (((2 * g + 1) ^ (m & 7)) << 4)); \
            _Pragma("unroll") for (int j = 0; j < 4; ++j) {                           \
                KD[j] = q0[j]; KD[4 + j] = q1[j];                                     \
            }                                                                         \
        }                                                                             \
    }

__global__ __launch_bounds__(512, 1) void dde_8p(
    const float* __restrict__ ts, const float* __restrict__ y0,
    const float* __restrict__ W0, const float* __restrict__ b0,
    const float* __restrict__ W1, const float* __restrict__ b1,
    const float* __restrict__ W2, const float* __restrict__ b2,
    const float* __restrict__ W3, const float* __restrict__ b3,
    float* __restrict__ out)
{
    __shared__ __align__(16) char hists[WSLOTS * 1280]; // [slot][m][32bf16], 80-B rows
    __shared__ __align__(16) char xb0[2 * 1280];        // [dl][m][32bf16] lerp buffers
    __shared__ __align__(16) char xb1[2 * 1280];
    __shared__ __align__(16) char xb2[2 * 1280];
    __shared__ __align__(16) char hA[16 * 256];
    __shared__ __align__(16) char hB[16 * 256];
    __shared__ __align__(16) char kbuf[16 * 128];       // k D-layout f32, swizzled
    __shared__ float tsb[TT];
    // ~85 KB LDS, 1 block/CU, 8 waves = 2 per SIMD

    const int tid  = threadIdx.x;
    const int lane = tid & 63;
    const int wv   = tid >> 6;        // wave 0..7 -> one N-tile of hidden layers
    const int m    = lane & 15;       // batch row within block
    const int g    = lane >> 4;       // feature-octet index
    const int tbB2 = wv * 32;         // byte base of this wave's hidden tile
    const int sw   = (m & 7) << 4;
    const int R0   = blockIdx.x * 16;

    for (int idx = tid; idx < WSLOTS * 320; idx += 512) ((unsigned*)hists)[idx] = 0u;
    if (tid < TT) tsb[tid] = ts[tid];

    // ---- register-resident weight fragments ----
    bf16x8 W0f[3], W1f[4], W2f[4], W3f[4];
    {
        const int rw = wv * 16 + m;
        #pragma unroll
        for (int kc = 0; kc < 3; ++kc) W0f[kc] = ldw8(W0 + rw * 96 + kc * 32 + g * 8);
        #pragma unroll
        for (int kc = 0; kc < 4; ++kc) W1f[kc] = ldw8(W1 + rw * 128 + kc * 32 + g * 8);
        #pragma unroll
        for (int kc = 0; kc < 4; ++kc) W2f[kc] = ldw8(W2 + rw * 128 + kc * 32 + g * 8);
        const int rw3 = (wv & 1) * 16 + m;   // only waves 0/1 use W3f
        #pragma unroll
        for (int kc = 0; kc < 4; ++kc) W3f[kc] = ldw8(W3 + rw3 * 128 + kc * 32 + g * 8);
    }
    f32x4 bias0, bias1, bias2, bias3;
    bias0 = *(const f32x4*)(b0 + wv * 16 + g * 4);
    bias1 = *(const f32x4*)(b1 + wv * 16 + g * 4);
    bias2 = *(const f32x4*)(b2 + wv * 16 + g * 4);
    bias3 = *(const f32x4*)(b3 + (wv & 1) * 16 + g * 4);

    __syncthreads();   // hist zero complete

    // ---- state init: y/k replicated in ALL waves, B-layout fp32 ----
    float y[8], k1[8], k2[8], k3[8];
    {
        float4 v0 = *(const float4*)(y0 + (R0 + m) * DATA + g * 8);
        float4 v1 = *(const float4*)(y0 + (R0 + m) * DATA + g * 8 + 4);
        y[0] = v0.x; y[1] = v0.y; y[2] = v0.z; y[3] = v0.w;
        y[4] = v1.x; y[5] = v1.y; y[6] = v1.z; y[7] = v1.w;
        #pragma unroll
        for (int e = 0; e < 8; ++e) { k1[e] = 0.0f; k2[e] = 0.0f; k3[e] = 0.0f; }
        if (wv == 0) {
            bfp4 p;
            #pragma unroll
            for (int e = 0; e < 8; ++e) p.b[e] = (__bf16)y[e];
            *(bf16x8*)(hists + m * 80 + g * 16) = p.v;        // hist slot 0 = y0
            *(float4*)(out + (R0 + m) * DATA + g * 8) = v0;   // ys[0] = y0 exact
            *(float4*)(out + (R0 + m) * DATA + g * 8 + 4) = v1;
        }
    }
    if (blockIdx.x == 0 && tid == 0)
        out[(size_t)TT * BATCH * DATA] = 255.0f;   // tuple output 1: int32(T-1)
    __syncthreads();   // hist slot 0 visible

    const float t0v  = tsb[0];
    const float ivd0 = 1.0f / (tsb[1] - tsb[0]);

    // ---- prologue: fill all three stage lerp buffers for step 0 ----
    if (wv >= 2 && wv < 4) {
        const float dt0 = tsb[1] - tsb[0];
        PRELERP(t0v, xb0)
        PRELERP(fmaf(0.5f, dt0, t0v), xb1)
        PRELERP(fmaf(0.75f, dt0, t0v), xb2)
    }
    __syncthreads();

    // stage-1 lerp frags for step 0 (xb0)
    bf16x8 xlA, xlB, nl1, nl2;
    xlA = *(const bf16x8*)(xb0 + m * 80 + g * 16);
    xlB = *(const bf16x8*)(xb0 + 1280 + m * 80 + g * 16);

    #pragma unroll 1
    for (int i = 0; i < TT - 1; ++i) {
        const float t   = tsb[i];
        const float tn  = tsb[i + 1];
        const float dt  = tn - t;
        const float tnn = tsb[min(i + 2, TT - 1)];
        const float dtn = tnn - tn;          // 0 junk on final iteration (unused)

        // stage 1: consumes xlA/xlB (from xb0); SegD prefetches xb1 -> nl1/nl2,
        //          PRELERP writes xb2 (stage-3 time)
        DO_STAGE(0, 0.0f,  k1, k1, xlA, xlB, xb2, fmaf(0.75f, dt, t), xb1, nl1, nl2)
        // stage 2: consumes nl1/nl2 (xb1); SegD prefetches xb2 -> xlA/xlB,
        //          PRELERP writes xb0 (next-step stage-1 time)
        DO_STAGE(1, 0.5f,  k1, k2, nl1, nl2, xb0, tn, xb2, xlA, xlB)
        // stage 3: consumes xlA/xlB (xb2); SegD prefetches xb0 -> xlA/xlB for
        //          next step's stage 1; PRELERP writes xb1 (next-step stage-2)
        DO_STAGE(2, 0.75f, k2, k3, xlA, xlB, xb1, fmaf(0.5f, dtn, tn), xb0, xlA, xlB)

        {   // RK combine, replicated; hist/out stores by wave 0 (fire-and-forget)
            #pragma unroll
            for (int e = 0; e < 8; ++e) {
                const float ks = (2.0f / 9.0f) * k1[e] + (1.0f / 3.0f) * k2[e]
                               + (4.0f / 9.0f) * k3[e];
                y[e] = fmaf(dt, ks, y[e]);
            }
            if (wv == 0) {
                bfp4 p;
                #pragma unroll
                for (int e = 0; e < 8; ++e) p.b[e] = (__bf16)y[e];
                *(bf16x8*)(hists + ((i + 1) % WSLOTS) * 1280 + m * 80 + g * 16) = p.v;
                float4 o0, o1;
                o0.x = y[0]; o0.y = y[1]; o0.z = y[2]; o0.w = y[3];
                o1.x = y[4]; o1.y = y[5]; o1.z = y[6]; o1.w = y[7];
                float* op = out + (size_t)(i + 1) * BATCH * DATA + (R0 + m) * DATA + g * 8;
                *(float4*)op = o0;
                *(float4*)(op + 4) = o1;
            }
        }
        // Hazards (R17-identical + prefetch): each XNXT prefetch reads a buffer
        // last WRITTEN >=4 barriers earlier (xb1: written stage3-SegD prev step;
        // xb2: written stage1-SegD this step, read stage2-SegD = 4 barriers;
        // xb0: written stage2-SegD this step, read stage3-SegD = 4 barriers).
        // PRELERP writes in the same SegD target a DIFFERENT buffer than the
        // prefetch reads. kbuf: write SegD, b4, read; next write >=3 barriers.
        // hist slot i+1 written post-b4; first PRELERP read >=24 steps later.
    }
}

extern "C" void kernel_launch(void* const* d_in, const int* in_sizes, int n_in,
                              void* d_out, int out_size, void* d_ws, size_t ws_size,
                              hipStream_t stream) {
    const float* ts = (const float*)d_in[0];
    const float* y0 = (const float*)d_in[1];
    const float* W0 = (const float*)d_in[2];
    const float* b0 = (const float*)d_in[3];
    const float* W1 = (const float*)d_in[4];
    const float* b1 = (const float*)d_in[5];
    const float* W2 = (const float*)d_in[6];
    const float* b2 = (const float*)d_in[7];
    const float* W3 = (const float*)d_in[8];
    const float* b3 = (const float*)d_in[9];

    dde_8p<<<dim3(BATCH / 16), dim3(512), 0, stream>>>(
        ts, y0, W0, b0, W1, b1, W2, b2, W3, b3, (float*)d_out);
}